// Round 7
// baseline (720.108 us; speedup 1.0000x reference)
//
#include <hip/hip_runtime.h>
#include <hip/hip_bf16.h>
#include <hip/hip_fp16.h>

#define N_NODES 50000
#define N_EDGES 400000
#define N_GRAPHS 64
#define HEADS 4
#define GAT_DIM 128
#define FDIM 512   // HEADS*GAT_DIM
#define NEG_SLOPE 0.2f

typedef _Float16 f16x8 __attribute__((ext_vector_type(8)));
typedef float f32x4 __attribute__((ext_vector_type(4)));

// ---------------- CSR build ----------------
__global__ void deg_kernel(const int* __restrict__ edst, int* __restrict__ deg) {
    int e = blockIdx.x * blockDim.x + threadIdx.x;
    if (e < N_EDGES) atomicAdd(&deg[edst[e]], 1);
}

// single block, 1024 threads: exclusive scan of deg[N_NODES] -> off[N_NODES+1]
__global__ __launch_bounds__(1024) void scan_kernel(const int* __restrict__ deg,
                                                    int* __restrict__ off) {
    __shared__ int part[1024];
    const int n = N_NODES;
    int t = threadIdx.x;
    int chunk = (n + 1023) / 1024;
    int base = t * chunk;
    int s = 0;
    for (int i = 0; i < chunk; i++) {
        int idx = base + i;
        if (idx < n) s += deg[idx];
    }
    part[t] = s;
    __syncthreads();
    for (int d = 1; d < 1024; d <<= 1) {
        int add = (t >= d) ? part[t - d] : 0;
        __syncthreads();
        part[t] += add;
        __syncthreads();
    }
    int run = part[t] - s;  // exclusive prefix of this thread's chunk
    for (int i = 0; i < chunk; i++) {
        int idx = base + i;
        if (idx < n) { off[idx] = run; run += deg[idx]; }
    }
    if (t == 0) off[n] = part[1023];
}

__global__ void fill_kernel(const int* __restrict__ esrc, const int* __restrict__ edst,
                            const int* __restrict__ off, int* __restrict__ cursor,
                            int* __restrict__ csr_src) {
    int e = blockIdx.x * blockDim.x + threadIdx.x;
    if (e >= N_EDGES) return;
    int d = edst[e];
    int pos = off[d] + atomicAdd(&cursor[d], 1);
    csr_src[pos] = esrc[e];
}

// ---------------- weight prep: Wt[n][k] = concat(Wl,Wr)^T as fp16; bc = concat(bl,br) ----
__global__ __launch_bounds__(128) void wprep_kernel(const float* __restrict__ Wl,
                                                    const float* __restrict__ Wr,
                                                    const float* __restrict__ bl,
                                                    const float* __restrict__ br,
                                                    __half* __restrict__ Wt,
                                                    float* __restrict__ bc) {
    int n = blockIdx.x;   // 0..1023
    int k = threadIdx.x;  // 0..127
    float v = (n < 512) ? Wl[(size_t)k * 512 + n] : Wr[(size_t)k * 512 + (n - 512)];
    Wt[(size_t)n * 128 + k] = __float2half(v);
    if (k == 0) bc[n] = (n < 512) ? bl[n] : br[n - 512];
}

// ---------------- fp16 MFMA GEMM: out[M,1024] = A[M,128] @ [Wl|Wr] + bias ----------------
// R2: replaces fp32 VALU gemm (was 167us, VALUBusy 68%, MfmaUtil 0). fp16 in / fp32 accum.
// Block = 128x128 tile, 4 waves (2x2) x 64x64, K=128 LDS-resident. LDS rows padded to
// 136 halves (2-way bank alias = free). LDS-staged epilogue for dense 16B stores.
#define GTILE 128
#define LPAD 136
__global__ __launch_bounds__(256, 2) void gemm_mfma_kernel(const float* __restrict__ A,
                                                           const __half* __restrict__ Wt,
                                                           const float* __restrict__ bc,
                                                           __half* __restrict__ xl,
                                                           __half* __restrict__ xr, int M) {
    __shared__ __align__(16) _Float16 As[GTILE * LPAD];  // [m][k]
    __shared__ __align__(16) _Float16 Bs[GTILE * LPAD];  // [n][k]
    const int cb = blockIdx.x;            // 0..7 column tile (0-3 -> xl, 4-7 -> xr)
    const int bm = blockIdx.y * GTILE;
    const int tid = threadIdx.x;

#pragma unroll
    for (int i = 0; i < 16; i++) {
        int ci = tid + 256 * i;
        int r = ci >> 5;
        int sk = (ci & 31) * 4;
        int gr = bm + r;
        float4 a = (gr < M) ? *(const float4*)(A + (size_t)gr * 128 + sk)
                            : make_float4(0.f, 0.f, 0.f, 0.f);
        union { _Float16 h[4]; float2 f2; } u;
        u.h[0] = (_Float16)a.x; u.h[1] = (_Float16)a.y;
        u.h[2] = (_Float16)a.z; u.h[3] = (_Float16)a.w;
        *(float2*)&As[r * LPAD + sk] = u.f2;
    }
#pragma unroll
    for (int i = 0; i < 8; i++) {
        int ci = tid + 256 * i;
        int r = ci >> 4;
        int sk = (ci & 15) * 8;
        f16x8 v = *(const f16x8*)(Wt + ((size_t)(cb * GTILE + r)) * 128 + sk);
        *(f16x8*)&Bs[r * LPAD + sk] = v;
    }
    __syncthreads();

    const int wid = tid >> 6, lane = tid & 63;
    const int wm = wid & 1, wn = wid >> 1;
    const int lm = lane & 15;
    const int lk = (lane >> 4) * 8;

    f32x4 acc[4][4];
#pragma unroll
    for (int fn = 0; fn < 4; fn++)
#pragma unroll
        for (int fm = 0; fm < 4; fm++) acc[fn][fm] = (f32x4){0.f, 0.f, 0.f, 0.f};

#pragma unroll
    for (int ks = 0; ks < 4; ks++) {
        f16x8 af[4], bf[4];
#pragma unroll
        for (int f = 0; f < 4; f++)
            af[f] = *(const f16x8*)&Bs[(wn * 64 + f * 16 + lm) * LPAD + ks * 32 + lk];
#pragma unroll
        for (int f = 0; f < 4; f++)
            bf[f] = *(const f16x8*)&As[(wm * 64 + f * 16 + lm) * LPAD + ks * 32 + lk];
#pragma unroll
        for (int fn = 0; fn < 4; fn++)
#pragma unroll
            for (int fm = 0; fm < 4; fm++)
                acc[fn][fm] = __builtin_amdgcn_mfma_f32_16x16x32_f16(af[fn], bf[fm],
                                                                     acc[fn][fm], 0, 0, 0);
    }

    __syncthreads();
    _Float16* Cs = As;
    const int lr4 = (lane >> 4) * 4;
#pragma unroll
    for (int fn = 0; fn < 4; fn++) {
        float4 b4 = *(const float4*)(bc + cb * GTILE + wn * 64 + fn * 16 + lr4);
#pragma unroll
        for (int fm = 0; fm < 4; fm++) {
            f32x4 v = acc[fn][fm];
            union { _Float16 h[4]; float2 f2; } u;
            u.h[0] = (_Float16)(v[0] + b4.x);
            u.h[1] = (_Float16)(v[1] + b4.y);
            u.h[2] = (_Float16)(v[2] + b4.z);
            u.h[3] = (_Float16)(v[3] + b4.w);
            int m_loc = wm * 64 + fm * 16 + lm;
            int n_loc = wn * 64 + fn * 16 + lr4;
            *(float2*)&Cs[m_loc * LPAD + n_loc] = u.f2;
        }
    }
    __syncthreads();

    __half* dst = (cb < 4) ? xl : xr;
    const int c0 = (cb & 3) * GTILE;
#pragma unroll
    for (int i = 0; i < 8; i++) {
        int ci = tid + 256 * i;
        int r = ci >> 4;
        int ck = (ci & 15) * 8;
        int gr = bm + r;
        if (gr < M) {
            float4 v = *(const float4*)&Cs[r * LPAD + ck];
            *(float4*)(dst + (size_t)gr * 512 + c0 + ck) = v;
        }
    }
}

#define LK(mm) fmaf(fminf(mm, 0.f), NEG_SLOPE, fmaxf(mm, 0.f))

// ------- LAYER 0, R6: 4-edge BATCHED online softmax ----------------
// Theories refuted so far: degree raggedness (R3), CP dispatch rate (R4), occupancy/TLP
// (R5: 2048 vs 1024 blocks = null, VALUBusy pinned 63%). Survivor: per-edge serial chain
// (score -> 4 chained shfl (DS) -> exp -> loop-carried rescale). Batch 4 edges: 4
// independent scores + 4 independent shfl chains (pipelined), ONE combined softmax
// update per batch -> loop-carried dep fires 1/4 as often; exp 8->5, accum 64->40 per
// 4 edges. Invalid tail slots: part=-1e30 (w=0), v=0.
#define EW0_BLOCKS 2048
#define EW0_NW (EW0_BLOCKS * 4)
__global__ __launch_bounds__(256) void fused_edge0_kernel(const int* __restrict__ off,
                                                          const int* __restrict__ csr_src,
                                                          const float* __restrict__ x,
                                                          const float* __restrict__ Wl,
                                                          const float* __restrict__ bl,
                                                          const float* __restrict__ Wr,
                                                          const float* __restrict__ br,
                                                          const float* __restrict__ att,
                                                          const float* __restrict__ bias,
                                                          float* __restrict__ hout) {
    const int lane = threadIdx.x & 63;
    const int wglob = blockIdx.x * 4 + (threadIdx.x >> 6);
    const int loff = lane * 8;
    float4 wl00 = *(const float4*)(Wl + loff),        wl01 = *(const float4*)(Wl + loff + 4);
    float4 wl10 = *(const float4*)(Wl + 512 + loff),  wl11 = *(const float4*)(Wl + 512 + loff + 4);
    float4 wl20 = *(const float4*)(Wl + 1024 + loff), wl21 = *(const float4*)(Wl + 1024 + loff + 4);
    float4 bl0  = *(const float4*)(bl + loff),        bl1  = *(const float4*)(bl + loff + 4);
    float4 at0  = *(const float4*)(att + loff),       at1  = *(const float4*)(att + loff + 4);
    float4 wr00 = *(const float4*)(Wr + loff),        wr01 = *(const float4*)(Wr + loff + 4);
    float4 wr10 = *(const float4*)(Wr + 512 + loff),  wr11 = *(const float4*)(Wr + 512 + loff + 4);
    float4 wr20 = *(const float4*)(Wr + 1024 + loff), wr21 = *(const float4*)(Wr + 1024 + loff + 4);
    float4 br0  = *(const float4*)(br + loff),        br1  = *(const float4*)(br + loff + 4);

    for (int n = wglob; n < N_NODES; n += EW0_NW) {
        int s = off[n], e = off[n + 1];
        float xn0 = x[n * 3 + 0], xn1 = x[n * 3 + 1], xn2 = x[n * 3 + 2];
        float4 xr0, xr1;
        xr0.x = fmaf(xn0, wr00.x, fmaf(xn1, wr10.x, fmaf(xn2, wr20.x, br0.x)));
        xr0.y = fmaf(xn0, wr00.y, fmaf(xn1, wr10.y, fmaf(xn2, wr20.y, br0.y)));
        xr0.z = fmaf(xn0, wr00.z, fmaf(xn1, wr10.z, fmaf(xn2, wr20.z, br0.z)));
        xr0.w = fmaf(xn0, wr00.w, fmaf(xn1, wr10.w, fmaf(xn2, wr20.w, br0.w)));
        xr1.x = fmaf(xn0, wr01.x, fmaf(xn1, wr11.x, fmaf(xn2, wr21.x, br1.x)));
        xr1.y = fmaf(xn0, wr01.y, fmaf(xn1, wr11.y, fmaf(xn2, wr21.y, br1.y)));
        xr1.z = fmaf(xn0, wr01.z, fmaf(xn1, wr11.z, fmaf(xn2, wr21.z, br1.z)));
        xr1.w = fmaf(xn0, wr01.w, fmaf(xn1, wr11.w, fmaf(xn2, wr21.w, br1.w)));

        float mx = -1e30f, denom = 0.f;
        float a0 = 0.f, a1 = 0.f, a2 = 0.f, a3 = 0.f, a4 = 0.f, a5 = 0.f, a6 = 0.f, a7 = 0.f;

        for (int p = s; p < e; p += 4) {
            int nb = e - p; if (nb > 4) nb = 4;
            float cx0[4], cx1[4], cx2[4];
#pragma unroll
            for (int i = 0; i < 4; i++) {
                if (i < nb) {
                    int id = csr_src[p + i];
                    cx0[i] = x[id * 3]; cx1[i] = x[id * 3 + 1]; cx2[i] = x[id * 3 + 2];
                } else { cx0[i] = 0.f; cx1[i] = 0.f; cx2[i] = 0.f; }
            }
            float4 v0s[4], v1s[4];
            float part[4];
#pragma unroll
            for (int i = 0; i < 4; i++) {
                if (i < nb) {
                    float4 v0, v1;
                    v0.x = fmaf(cx0[i], wl00.x, fmaf(cx1[i], wl10.x, fmaf(cx2[i], wl20.x, bl0.x)));
                    v0.y = fmaf(cx0[i], wl00.y, fmaf(cx1[i], wl10.y, fmaf(cx2[i], wl20.y, bl0.y)));
                    v0.z = fmaf(cx0[i], wl00.z, fmaf(cx1[i], wl10.z, fmaf(cx2[i], wl20.z, bl0.z)));
                    v0.w = fmaf(cx0[i], wl00.w, fmaf(cx1[i], wl10.w, fmaf(cx2[i], wl20.w, bl0.w)));
                    v1.x = fmaf(cx0[i], wl01.x, fmaf(cx1[i], wl11.x, fmaf(cx2[i], wl21.x, bl1.x)));
                    v1.y = fmaf(cx0[i], wl01.y, fmaf(cx1[i], wl11.y, fmaf(cx2[i], wl21.y, bl1.y)));
                    v1.z = fmaf(cx0[i], wl01.z, fmaf(cx1[i], wl11.z, fmaf(cx2[i], wl21.z, bl1.z)));
                    v1.w = fmaf(cx0[i], wl01.w, fmaf(cx1[i], wl11.w, fmaf(cx2[i], wl21.w, bl1.w)));
                    float pt;
                    pt = LK(v0.x + xr0.x) * at0.x;
                    pt = fmaf(LK(v0.y + xr0.y), at0.y, pt);
                    pt = fmaf(LK(v0.z + xr0.z), at0.z, pt);
                    pt = fmaf(LK(v0.w + xr0.w), at0.w, pt);
                    pt = fmaf(LK(v1.x + xr1.x), at1.x, pt);
                    pt = fmaf(LK(v1.y + xr1.y), at1.y, pt);
                    pt = fmaf(LK(v1.z + xr1.z), at1.z, pt);
                    pt = fmaf(LK(v1.w + xr1.w), at1.w, pt);
                    v0s[i] = v0; v1s[i] = v1; part[i] = pt;
                } else {
                    v0s[i] = make_float4(0.f, 0.f, 0.f, 0.f);
                    v1s[i] = make_float4(0.f, 0.f, 0.f, 0.f);
                    part[i] = -1e30f;
                }
            }
#pragma unroll
            for (int i = 0; i < 4; i++) {
                part[i] += __shfl_xor(part[i], 1);
                part[i] += __shfl_xor(part[i], 2);
                part[i] += __shfl_xor(part[i], 4);
                part[i] += __shfl_xor(part[i], 8);
            }
            float m4 = fmaxf(fmaxf(part[0], part[1]), fmaxf(part[2], part[3]));
            float mnew = fmaxf(mx, m4);
            float scale = __expf(mx - mnew);
            float w0 = __expf(part[0] - mnew);
            float w1 = __expf(part[1] - mnew);
            float w2 = __expf(part[2] - mnew);
            float w3 = __expf(part[3] - mnew);
            denom = fmaf(denom, scale, (w0 + w1) + (w2 + w3));
            a0 = fmaf(a0, scale, fmaf(w3, v0s[3].x, fmaf(w2, v0s[2].x, fmaf(w1, v0s[1].x, w0 * v0s[0].x))));
            a1 = fmaf(a1, scale, fmaf(w3, v0s[3].y, fmaf(w2, v0s[2].y, fmaf(w1, v0s[1].y, w0 * v0s[0].y))));
            a2 = fmaf(a2, scale, fmaf(w3, v0s[3].z, fmaf(w2, v0s[2].z, fmaf(w1, v0s[1].z, w0 * v0s[0].z))));
            a3 = fmaf(a3, scale, fmaf(w3, v0s[3].w, fmaf(w2, v0s[2].w, fmaf(w1, v0s[1].w, w0 * v0s[0].w))));
            a4 = fmaf(a4, scale, fmaf(w3, v1s[3].x, fmaf(w2, v1s[2].x, fmaf(w1, v1s[1].x, w0 * v1s[0].x))));
            a5 = fmaf(a5, scale, fmaf(w3, v1s[3].y, fmaf(w2, v1s[2].y, fmaf(w1, v1s[1].y, w0 * v1s[0].y))));
            a6 = fmaf(a6, scale, fmaf(w3, v1s[3].z, fmaf(w2, v1s[2].z, fmaf(w1, v1s[1].z, w0 * v1s[0].z))));
            a7 = fmaf(a7, scale, fmaf(w3, v1s[3].w, fmaf(w2, v1s[2].w, fmaf(w1, v1s[1].w, w0 * v1s[0].w))));
            mx = mnew;
        }
        float inv = denom > 0.f ? 1.f / denom : 0.f;
        a0 *= inv; a1 *= inv; a2 *= inv; a3 *= inv;
        a4 *= inv; a5 *= inv; a6 *= inv; a7 *= inv;
        a0 += __shfl_xor(a0, 16); a0 += __shfl_xor(a0, 32);
        a1 += __shfl_xor(a1, 16); a1 += __shfl_xor(a1, 32);
        a2 += __shfl_xor(a2, 16); a2 += __shfl_xor(a2, 32);
        a3 += __shfl_xor(a3, 16); a3 += __shfl_xor(a3, 32);
        a4 += __shfl_xor(a4, 16); a4 += __shfl_xor(a4, 32);
        a5 += __shfl_xor(a5, 16); a5 += __shfl_xor(a5, 32);
        a6 += __shfl_xor(a6, 16); a6 += __shfl_xor(a6, 32);
        a7 += __shfl_xor(a7, 16); a7 += __shfl_xor(a7, 32);
        if (lane < 16) {
            float4 b0 = *(const float4*)(bias + lane * 8);
            float4 b1 = *(const float4*)(bias + lane * 8 + 4);
            float o[8];
            o[0] = fmaf(0.25f, a0, b0.x); o[1] = fmaf(0.25f, a1, b0.y);
            o[2] = fmaf(0.25f, a2, b0.z); o[3] = fmaf(0.25f, a3, b0.w);
            o[4] = fmaf(0.25f, a4, b1.x); o[5] = fmaf(0.25f, a5, b1.y);
            o[6] = fmaf(0.25f, a6, b1.z); o[7] = fmaf(0.25f, a7, b1.w);
#pragma unroll
            for (int j = 0; j < 8; j++) o[j] = o[j] > 0.f ? o[j] : (__expf(o[j]) - 1.f);
            *(float4*)(hout + (size_t)n * GAT_DIM + lane * 8) = make_float4(o[0], o[1], o[2], o[3]);
            *(float4*)(hout + (size_t)n * GAT_DIM + lane * 8 + 4) = make_float4(o[4], o[5], o[6], o[7]);
        }
    }
}

// ------- layers 1/2, R6: 4-edge BATCHED online softmax + 1-batch-ahead row prefetch ----
// Non-persistent 4-nodes/block (R5: dynamic block scheduling beats static striding here).
// fp16 xl/xr gather (1KB/edge); fp32 accumulation.
__global__ __launch_bounds__(256) void fused_edge_kernel(const int* __restrict__ off,
                                                         const int* __restrict__ csr_src,
                                                         const __half* __restrict__ xl,
                                                         const __half* __restrict__ xr,
                                                         const float* __restrict__ att,
                                                         const float* __restrict__ bias,
                                                         float* __restrict__ hout) {
    int wid = threadIdx.x >> 6;
    int lane = threadIdx.x & 63;
    int n = blockIdx.x * 4 + wid;
    if (n >= N_NODES) return;
    int s = off[n], e = off[n + 1];
    const int loff = lane * 8;
    float4 xr0, xr1;
    {
        float4 rxr = *(const float4*)(xr + (size_t)n * FDIM + loff);
        const __half2* xp = (const __half2*)&rxr;
        float2 x01 = __half22float2(xp[0]);
        float2 x23 = __half22float2(xp[1]);
        float2 x45 = __half22float2(xp[2]);
        float2 x67 = __half22float2(xp[3]);
        xr0 = make_float4(x01.x, x01.y, x23.x, x23.y);
        xr1 = make_float4(x45.x, x45.y, x67.x, x67.y);
    }
    float4 at0 = *(const float4*)(att + loff);
    float4 at1 = *(const float4*)(att + loff + 4);

    float mx = -1e30f, denom = 0.f;
    float a0 = 0.f, a1 = 0.f, a2 = 0.f, a3 = 0.f, a4 = 0.f, a5 = 0.f, a6 = 0.f, a7 = 0.f;

    int p = s;
    int nbc = e - p; if (nbc > 4) nbc = 4; if (nbc < 0) nbc = 0;
    float4 c0[4];
#pragma unroll
    for (int i = 0; i < 4; i++) {
        if (i < nbc) c0[i] = *(const float4*)(xl + (size_t)csr_src[p + i] * FDIM + loff);
    }
    while (p < e) {
        int pn = p + 4;
        int nbn = e - pn; if (nbn > 4) nbn = 4; if (nbn < 0) nbn = 0;
        float4 nx[4];
#pragma unroll
        for (int i = 0; i < 4; i++) {
            if (i < nbn) nx[i] = *(const float4*)(xl + (size_t)csr_src[pn + i] * FDIM + loff);
        }
        float4 v0s[4], v1s[4];
        float part[4];
#pragma unroll
        for (int i = 0; i < 4; i++) {
            if (i < nbc) {
                const __half2* hp = (const __half2*)&c0[i];
                float2 f01 = __half22float2(hp[0]);
                float2 f23 = __half22float2(hp[1]);
                float2 f45 = __half22float2(hp[2]);
                float2 f67 = __half22float2(hp[3]);
                float4 v0 = make_float4(f01.x, f01.y, f23.x, f23.y);
                float4 v1 = make_float4(f45.x, f45.y, f67.x, f67.y);
                float pt;
                pt = LK(v0.x + xr0.x) * at0.x;
                pt = fmaf(LK(v0.y + xr0.y), at0.y, pt);
                pt = fmaf(LK(v0.z + xr0.z), at0.z, pt);
                pt = fmaf(LK(v0.w + xr0.w), at0.w, pt);
                pt = fmaf(LK(v1.x + xr1.x), at1.x, pt);
                pt = fmaf(LK(v1.y + xr1.y), at1.y, pt);
                pt = fmaf(LK(v1.z + xr1.z), at1.z, pt);
                pt = fmaf(LK(v1.w + xr1.w), at1.w, pt);
                v0s[i] = v0; v1s[i] = v1; part[i] = pt;
            } else {
                v0s[i] = make_float4(0.f, 0.f, 0.f, 0.f);
                v1s[i] = make_float4(0.f, 0.f, 0.f, 0.f);
                part[i] = -1e30f;
            }
        }
#pragma unroll
        for (int i = 0; i < 4; i++) {
            part[i] += __shfl_xor(part[i], 1);
            part[i] += __shfl_xor(part[i], 2);
            part[i] += __shfl_xor(part[i], 4);
            part[i] += __shfl_xor(part[i], 8);
        }
        float m4 = fmaxf(fmaxf(part[0], part[1]), fmaxf(part[2], part[3]));
        float mnew = fmaxf(mx, m4);
        float scale = __expf(mx - mnew);
        float w0 = __expf(part[0] - mnew);
        float w1 = __expf(part[1] - mnew);
        float w2 = __expf(part[2] - mnew);
        float w3 = __expf(part[3] - mnew);
        denom = fmaf(denom, scale, (w0 + w1) + (w2 + w3));
        a0 = fmaf(a0, scale, fmaf(w3, v0s[3].x, fmaf(w2, v0s[2].x, fmaf(w1, v0s[1].x, w0 * v0s[0].x))));
        a1 = fmaf(a1, scale, fmaf(w3, v0s[3].y, fmaf(w2, v0s[2].y, fmaf(w1, v0s[1].y, w0 * v0s[0].y))));
        a2 = fmaf(a2, scale, fmaf(w3, v0s[3].z, fmaf(w2, v0s[2].z, fmaf(w1, v0s[1].z, w0 * v0s[0].z))));
        a3 = fmaf(a3, scale, fmaf(w3, v0s[3].w, fmaf(w2, v0s[2].w, fmaf(w1, v0s[1].w, w0 * v0s[0].w))));
        a4 = fmaf(a4, scale, fmaf(w3, v1s[3].x, fmaf(w2, v1s[2].x, fmaf(w1, v1s[1].x, w0 * v1s[0].x))));
        a5 = fmaf(a5, scale, fmaf(w3, v1s[3].y, fmaf(w2, v1s[2].y, fmaf(w1, v1s[1].y, w0 * v1s[0].y))));
        a6 = fmaf(a6, scale, fmaf(w3, v1s[3].z, fmaf(w2, v1s[2].z, fmaf(w1, v1s[1].z, w0 * v1s[0].z))));
        a7 = fmaf(a7, scale, fmaf(w3, v1s[3].w, fmaf(w2, v1s[2].w, fmaf(w1, v1s[1].w, w0 * v1s[0].w))));
        mx = mnew;
#pragma unroll
        for (int i = 0; i < 4; i++) c0[i] = nx[i];
        nbc = nbn; p = pn;
    }
    float inv = denom > 0.f ? 1.f / denom : 0.f;
    a0 *= inv; a1 *= inv; a2 *= inv; a3 *= inv;
    a4 *= inv; a5 *= inv; a6 *= inv; a7 *= inv;
    a0 += __shfl_xor(a0, 16); a0 += __shfl_xor(a0, 32);
    a1 += __shfl_xor(a1, 16); a1 += __shfl_xor(a1, 32);
    a2 += __shfl_xor(a2, 16); a2 += __shfl_xor(a2, 32);
    a3 += __shfl_xor(a3, 16); a3 += __shfl_xor(a3, 32);
    a4 += __shfl_xor(a4, 16); a4 += __shfl_xor(a4, 32);
    a5 += __shfl_xor(a5, 16); a5 += __shfl_xor(a5, 32);
    a6 += __shfl_xor(a6, 16); a6 += __shfl_xor(a6, 32);
    a7 += __shfl_xor(a7, 16); a7 += __shfl_xor(a7, 32);
    if (lane < 16) {
        float4 b0 = *(const float4*)(bias + lane * 8);
        float4 b1 = *(const float4*)(bias + lane * 8 + 4);
        float o[8];
        o[0] = fmaf(0.25f, a0, b0.x); o[1] = fmaf(0.25f, a1, b0.y);
        o[2] = fmaf(0.25f, a2, b0.z); o[3] = fmaf(0.25f, a3, b0.w);
        o[4] = fmaf(0.25f, a4, b1.x); o[5] = fmaf(0.25f, a5, b1.y);
        o[6] = fmaf(0.25f, a6, b1.z); o[7] = fmaf(0.25f, a7, b1.w);
#pragma unroll
        for (int j = 0; j < 8; j++) o[j] = o[j] > 0.f ? o[j] : (__expf(o[j]) - 1.f);
        *(float4*)(hout + (size_t)n * GAT_DIM + lane * 8) = make_float4(o[0], o[1], o[2], o[3]);
        *(float4*)(hout + (size_t)n * GAT_DIM + lane * 8 + 4) = make_float4(o[4], o[5], o[6], o[7]);
    }
}

// ---------------- mean pool over sorted batch (double accumulation) ----------------
#define POOL_CHUNK 64
__global__ __launch_bounds__(128) void pool_kernel(const float* __restrict__ h,
                                                   const int* __restrict__ batch,
                                                   double* __restrict__ psum,
                                                   int* __restrict__ pcnt) {
    int c = threadIdx.x;  // 0..127
    int n0 = blockIdx.x * POOL_CHUNK;
    int n1 = min(n0 + POOL_CHUNK, N_NODES);
    if (n0 >= N_NODES) return;
    double acc = 0.0;
    int cur = batch[n0];
    int cnt = 0;
    for (int n = n0; n < n1; n++) {
        int g = batch[n];
        if (g != cur) {
            atomicAdd(&psum[(size_t)cur * GAT_DIM + c], acc);
            if (c == 0) atomicAdd(&pcnt[cur], cnt);
            acc = 0.0; cnt = 0; cur = g;
        }
        acc += (double)h[(size_t)n * GAT_DIM + c];
        cnt++;
    }
    atomicAdd(&psum[(size_t)cur * GAT_DIM + c], acc);
    if (c == 0) atomicAdd(&pcnt[cur], cnt);
}

// ---------------- final linear: out[64,128] = g @ linW + linb ----------------
__global__ __launch_bounds__(128) void final_kernel(const double* __restrict__ psum,
                                                    const int* __restrict__ pcnt,
                                                    const float* __restrict__ linW,
                                                    const float* __restrict__ linb,
                                                    float* __restrict__ out) {
    int g = blockIdx.x;       // 0..63
    int j = threadIdx.x;      // 0..127
    __shared__ float gv[128];
    float cnt = (float)max(pcnt[g], 1);
    gv[j] = (float)(psum[(size_t)g * 128 + j] / (double)cnt);
    __syncthreads();
    float acc = 0.f;
    for (int c = 0; c < 128; c++) acc = fmaf(gv[c], linW[c * 128 + j], acc);
    out[(size_t)g * 128 + j] = acc + linb[j];
}

extern "C" void kernel_launch(void* const* d_in, const int* in_sizes, int n_in,
                              void* d_out, int out_size, void* d_ws, size_t ws_size,
                              hipStream_t stream) {
    const float* x    = (const float*)d_in[0];
    const int* eidx   = (const int*)d_in[1];
    const int* batch  = (const int*)d_in[2];
    const float* Wl[3] = {(const float*)d_in[3],  (const float*)d_in[9],  (const float*)d_in[15]};
    const float* bl[3] = {(const float*)d_in[4],  (const float*)d_in[10], (const float*)d_in[16]};
    const float* Wr[3] = {(const float*)d_in[5],  (const float*)d_in[11], (const float*)d_in[17]};
    const float* br[3] = {(const float*)d_in[6],  (const float*)d_in[12], (const float*)d_in[18]};
    const float* att[3] = {(const float*)d_in[7], (const float*)d_in[13], (const float*)d_in[19]};
    const float* bb[3] = {(const float*)d_in[8],  (const float*)d_in[14], (const float*)d_in[20]};
    const float* linW = (const float*)d_in[21];
    const float* linb = (const float*)d_in[22];
    float* out = (float*)d_out;

    const int* esrc = eidx;
    const int* edst = eidx + N_EDGES;

    // workspace carve-up (256B aligned)
    char* p = (char*)d_ws;
    auto alloc = [&](size_t bytes) { void* r = (void*)p; p += (bytes + 255) & ~(size_t)255; return r; };
    __half* xl     = (__half*)alloc((size_t)N_NODES * FDIM * 2);  // 51.2 MB (fp16)
    __half* xr     = (__half*)alloc((size_t)N_NODES * FDIM * 2);  // 51.2 MB (fp16)
    float* hbuf    = (float*)alloc((size_t)N_NODES * GAT_DIM * 4);// 25.6 MB
    int*   off     = (int*)alloc((size_t)(N_NODES + 1) * 4);
    int*   csr_src = (int*)alloc((size_t)N_EDGES * 4);
    __half* Wt1    = (__half*)alloc((size_t)1024 * 128 * 2);
    __half* Wt2    = (__half*)alloc((size_t)1024 * 128 * 2);
    float* bc1     = (float*)alloc((size_t)1024 * 4);
    float* bc2     = (float*)alloc((size_t)1024 * 4);
    // --- contiguous zero region: deg, cursor, psum, pcnt ---
    char* zbase = p;
    int*   deg     = (int*)alloc((size_t)N_NODES * 4);
    int*   cursor  = (int*)alloc((size_t)N_NODES * 4);
    double* psum   = (double*)alloc((size_t)N_GRAPHS * GAT_DIM * 8);
    int*   pcnt    = (int*)alloc((size_t)N_GRAPHS * 4);
    size_t zbytes = (size_t)(p - zbase);

    hipMemsetAsync(zbase, 0, zbytes, stream);

    // CSR build + weight prep
    deg_kernel<<<(N_EDGES + 255) / 256, 256, 0, stream>>>(edst, deg);
    scan_kernel<<<1, 1024, 0, stream>>>(deg, off);
    fill_kernel<<<(N_EDGES + 255) / 256, 256, 0, stream>>>(esrc, edst, off, cursor, csr_src);
    wprep_kernel<<<1024, 128, 0, stream>>>(Wl[1], Wr[1], bl[1], br[1], Wt1, bc1);
    wprep_kernel<<<1024, 128, 0, stream>>>(Wl[2], Wr[2], bl[2], br[2], Wt2, bc2);

    dim3 ggrid(8, (N_NODES + GTILE - 1) / GTILE);
    const int egrid = (N_NODES + 3) / 4;  // 4 nodes (waves) per 256-thr block

    // layer 0: fully fused (K=3 transform recomputed per edge), persistent full-occupancy
    fused_edge0_kernel<<<EW0_BLOCKS, 256, 0, stream>>>(off, csr_src, x, Wl[0], bl[0],
                                                       Wr[0], br[0], att[0], bb[0], hbuf);
    // layers 1,2
    __half* Wt[3] = {nullptr, Wt1, Wt2};
    float*  bc[3] = {nullptr, bc1, bc2};
    for (int l = 1; l < 3; l++) {
        gemm_mfma_kernel<<<ggrid, 256, 0, stream>>>(hbuf, Wt[l], bc[l], xl, xr, N_NODES);
        fused_edge_kernel<<<egrid, 256, 0, stream>>>(off, csr_src, xl, xr,
                                                     att[l], bb[l], hbuf);
    }

    pool_kernel<<<(N_NODES + POOL_CHUNK - 1) / POOL_CHUNK, 128, 0, stream>>>(hbuf, batch, psum, pcnt);
    final_kernel<<<N_GRAPHS, 128, 0, stream>>>(psum, pcnt, linW, linb, out);
}

// Round 8
// 615.774 us; speedup vs baseline: 1.1694x; 1.1694x over previous
//
#include <hip/hip_runtime.h>
#include <hip/hip_bf16.h>
#include <hip/hip_fp16.h>

#define N_NODES 50000
#define N_EDGES 400000
#define N_GRAPHS 64
#define HEADS 4
#define GAT_DIM 128
#define FDIM 512   // HEADS*GAT_DIM
#define NEG_SLOPE 0.2f

typedef _Float16 f16x8 __attribute__((ext_vector_type(8)));
typedef float f32x4 __attribute__((ext_vector_type(4)));

// ---------------- CSR build ----------------
__global__ void deg_kernel(const int* __restrict__ edst, int* __restrict__ deg) {
    int e = blockIdx.x * blockDim.x + threadIdx.x;
    if (e < N_EDGES) atomicAdd(&deg[edst[e]], 1);
}

// single block, 1024 threads: exclusive scan of deg[N_NODES] -> off[N_NODES+1]
__global__ __launch_bounds__(1024) void scan_kernel(const int* __restrict__ deg,
                                                    int* __restrict__ off) {
    __shared__ int part[1024];
    const int n = N_NODES;
    int t = threadIdx.x;
    int chunk = (n + 1023) / 1024;
    int base = t * chunk;
    int s = 0;
    for (int i = 0; i < chunk; i++) {
        int idx = base + i;
        if (idx < n) s += deg[idx];
    }
    part[t] = s;
    __syncthreads();
    for (int d = 1; d < 1024; d <<= 1) {
        int add = (t >= d) ? part[t - d] : 0;
        __syncthreads();
        part[t] += add;
        __syncthreads();
    }
    int run = part[t] - s;  // exclusive prefix of this thread's chunk
    for (int i = 0; i < chunk; i++) {
        int idx = base + i;
        if (idx < n) { off[idx] = run; run += deg[idx]; }
    }
    if (t == 0) off[n] = part[1023];
}

__global__ void fill_kernel(const int* __restrict__ esrc, const int* __restrict__ edst,
                            const int* __restrict__ off, int* __restrict__ cursor,
                            int* __restrict__ csr_src) {
    int e = blockIdx.x * blockDim.x + threadIdx.x;
    if (e >= N_EDGES) return;
    int d = edst[e];
    int pos = off[d] + atomicAdd(&cursor[d], 1);
    csr_src[pos] = esrc[e];
}

// ---------------- weight prep: Wt[n][k] = concat(Wl,Wr)^T as fp16; bc = concat(bl,br) ----
__global__ __launch_bounds__(128) void wprep_kernel(const float* __restrict__ Wl,
                                                    const float* __restrict__ Wr,
                                                    const float* __restrict__ bl,
                                                    const float* __restrict__ br,
                                                    __half* __restrict__ Wt,
                                                    float* __restrict__ bc) {
    int n = blockIdx.x;   // 0..1023
    int k = threadIdx.x;  // 0..127
    float v = (n < 512) ? Wl[(size_t)k * 512 + n] : Wr[(size_t)k * 512 + (n - 512)];
    Wt[(size_t)n * 128 + k] = __float2half(v);
    if (k == 0) bc[n] = (n < 512) ? bl[n] : br[n - 512];
}

// ---------------- fp16 MFMA GEMM, R7: A-panel reuse ----------------
// R2-R6 grid was (8 col-tiles, 391 M-tiles): every col tile re-staged the full A panel
// -> 8 x 25.6MB = 205MB A reads/dispatch (vs 25.6 ideal). R7: one block per 64-row
// M-tile loops all 8 col tiles in-block; A staged to LDS ONCE (fp16), Bs per cb.
// LDS 50.7KB -> 3 blocks/CU. Fragment mapping byte-identical to the verified R2 kernel
// (wave tiling 2x2 -> 32Mx64N per wave). Arithmetic order per output unchanged ->
// xl/xr bitwise identical (absmax must stay 3.814697e-06).
#define GM 64
#define GP 132
__global__ __launch_bounds__(256) void gemm_mfma_kernel(const float* __restrict__ A,
                                                        const __half* __restrict__ Wt,
                                                        const float* __restrict__ bc,
                                                        __half* __restrict__ xl,
                                                        __half* __restrict__ xr, int M) {
    __shared__ __align__(16) _Float16 As[GM * GP];     // [m][k] fp16, staged once
    __shared__ __align__(16) _Float16 Bs[128 * GP];    // [n][k] per col-tile; reused as Cs
    const int bm = blockIdx.x * GM;
    const int tid = threadIdx.x;

    // ---- stage A tile once: hbuf fp32 [64][128] -> fp16 ----
#pragma unroll
    for (int i = 0; i < 8; i++) {
        int ci = tid + 256 * i;           // 0..2047 float4-chunks
        int r = ci >> 5;                  // 0..63
        int k4 = (ci & 31) * 4;
        int gr = bm + r;
        float4 a = (gr < M) ? *(const float4*)(A + (size_t)gr * 128 + k4)
                            : make_float4(0.f, 0.f, 0.f, 0.f);
        union { _Float16 h[4]; float2 f2; } u;
        u.h[0] = (_Float16)a.x; u.h[1] = (_Float16)a.y;
        u.h[2] = (_Float16)a.z; u.h[3] = (_Float16)a.w;
        *(float2*)&As[r * GP + k4] = u.f2;
    }

    const int wid = tid >> 6, lane = tid & 63;
    const int wm = wid & 1, wn = wid >> 1;     // wave: m = wm*32.., n = wn*64..
    const int lm = lane & 15;
    const int lk = (lane >> 4) * 8;
    const int lr4 = (lane >> 4) * 4;

    for (int cb = 0; cb < 8; cb++) {
        __syncthreads();   // cb=0: As visible; cb>0: prior store-loop's Cs reads done
        // ---- stage Bs for this col tile ----
#pragma unroll
        for (int i = 0; i < 8; i++) {
            int ci = tid + 256 * i;       // 0..2047 16B-chunks
            int r = ci >> 4;              // 0..127
            int k8 = (ci & 15) * 8;
            *(f16x8*)&Bs[r * GP + k8] =
                *(const f16x8*)(Wt + ((size_t)(cb * 128 + r)) * 128 + k8);
        }
        __syncthreads();

        f32x4 acc[4][2];
#pragma unroll
        for (int fn = 0; fn < 4; fn++)
#pragma unroll
            for (int fm = 0; fm < 2; fm++) acc[fn][fm] = (f32x4){0.f, 0.f, 0.f, 0.f};

#pragma unroll
        for (int ks = 0; ks < 4; ks++) {
            f16x8 af[4], bf[2];
#pragma unroll
            for (int fn = 0; fn < 4; fn++)
                af[fn] = *(const f16x8*)&Bs[(wn * 64 + fn * 16 + lm) * GP + ks * 32 + lk];
#pragma unroll
            for (int fm = 0; fm < 2; fm++)
                bf[fm] = *(const f16x8*)&As[(wm * 32 + fm * 16 + lm) * GP + ks * 32 + lk];
#pragma unroll
            for (int fn = 0; fn < 4; fn++)
#pragma unroll
                for (int fm = 0; fm < 2; fm++)
                    acc[fn][fm] = __builtin_amdgcn_mfma_f32_16x16x32_f16(af[fn], bf[fm],
                                                                         acc[fn][fm], 0, 0, 0);
        }
        __syncthreads();   // all Bs fragment reads complete

        // ---- epilogue: bias + fp16 into Cs (=Bs space), then coalesced store ----
        _Float16* Cs = Bs;
#pragma unroll
        for (int fn = 0; fn < 4; fn++) {
            float4 b4 = *(const float4*)(bc + cb * 128 + wn * 64 + fn * 16 + lr4);
#pragma unroll
            for (int fm = 0; fm < 2; fm++) {
                f32x4 v = acc[fn][fm];
                union { _Float16 h[4]; float2 f2; } u;
                u.h[0] = (_Float16)(v[0] + b4.x);
                u.h[1] = (_Float16)(v[1] + b4.y);
                u.h[2] = (_Float16)(v[2] + b4.z);
                u.h[3] = (_Float16)(v[3] + b4.w);
                int m_loc = wm * 32 + fm * 16 + lm;
                int n_loc = wn * 64 + fn * 16 + lr4;
                *(float2*)&Cs[m_loc * GP + n_loc] = u.f2;
            }
        }
        __syncthreads();

        __half* dst = (cb < 4) ? xl : xr;
        const int c0 = (cb & 3) * 128;
#pragma unroll
        for (int i = 0; i < 4; i++) {
            int ci = tid + 256 * i;       // 0..1023 16B-chunks
            int r = ci >> 4;              // 0..63
            int c8 = (ci & 15) * 8;
            int gr = bm + r;
            if (gr < M) {
                float4 v = *(const float4*)&Cs[r * GP + c8];
                *(float4*)(dst + (size_t)gr * 512 + c0 + c8) = v;
            }
        }
    }
}

#define LK(mm) fmaf(fminf(mm, 0.f), NEG_SLOPE, fmaxf(mm, 0.f))

// ------- LAYER 0, R7: reverted to R5 form (best measured: 122us) ----------------
// R6 4-edge batching REGRESSED (129.6us, VGPR 76, masking SALU/branch overhead >
// savings). Issue-port model: VALUBusy x dur ~= 75-77us invariant across R4/R5/R6 ->
// SIMD issue saturated; only total-instruction reduction helps (future surgery).
#define EW0_BLOCKS 2048
#define EW0_NW (EW0_BLOCKS * 4)
__global__ __launch_bounds__(256) void fused_edge0_kernel(const int* __restrict__ off,
                                                          const int* __restrict__ csr_src,
                                                          const float* __restrict__ x,
                                                          const float* __restrict__ Wl,
                                                          const float* __restrict__ bl,
                                                          const float* __restrict__ Wr,
                                                          const float* __restrict__ br,
                                                          const float* __restrict__ att,
                                                          const float* __restrict__ bias,
                                                          float* __restrict__ hout) {
    const int lane = threadIdx.x & 63;
    const int wglob = blockIdx.x * 4 + (threadIdx.x >> 6);
    const int loff = lane * 8;
    float4 wl00 = *(const float4*)(Wl + loff),        wl01 = *(const float4*)(Wl + loff + 4);
    float4 wl10 = *(const float4*)(Wl + 512 + loff),  wl11 = *(const float4*)(Wl + 512 + loff + 4);
    float4 wl20 = *(const float4*)(Wl + 1024 + loff), wl21 = *(const float4*)(Wl + 1024 + loff + 4);
    float4 bl0  = *(const float4*)(bl + loff),        bl1  = *(const float4*)(bl + loff + 4);
    float4 at0  = *(const float4*)(att + loff),       at1  = *(const float4*)(att + loff + 4);
    float4 wr00 = *(const float4*)(Wr + loff),        wr01 = *(const float4*)(Wr + loff + 4);
    float4 wr10 = *(const float4*)(Wr + 512 + loff),  wr11 = *(const float4*)(Wr + 512 + loff + 4);
    float4 wr20 = *(const float4*)(Wr + 1024 + loff), wr21 = *(const float4*)(Wr + 1024 + loff + 4);
    float4 br0  = *(const float4*)(br + loff),        br1  = *(const float4*)(br + loff + 4);

    for (int n = wglob; n < N_NODES; n += EW0_NW) {
        int s = off[n], e = off[n + 1];
        float xn0 = x[n * 3 + 0], xn1 = x[n * 3 + 1], xn2 = x[n * 3 + 2];
        float4 xr0, xr1;
        xr0.x = fmaf(xn0, wr00.x, fmaf(xn1, wr10.x, fmaf(xn2, wr20.x, br0.x)));
        xr0.y = fmaf(xn0, wr00.y, fmaf(xn1, wr10.y, fmaf(xn2, wr20.y, br0.y)));
        xr0.z = fmaf(xn0, wr00.z, fmaf(xn1, wr10.z, fmaf(xn2, wr20.z, br0.z)));
        xr0.w = fmaf(xn0, wr00.w, fmaf(xn1, wr10.w, fmaf(xn2, wr20.w, br0.w)));
        xr1.x = fmaf(xn0, wr01.x, fmaf(xn1, wr11.x, fmaf(xn2, wr21.x, br1.x)));
        xr1.y = fmaf(xn0, wr01.y, fmaf(xn1, wr11.y, fmaf(xn2, wr21.y, br1.y)));
        xr1.z = fmaf(xn0, wr01.z, fmaf(xn1, wr11.z, fmaf(xn2, wr21.z, br1.z)));
        xr1.w = fmaf(xn0, wr01.w, fmaf(xn1, wr11.w, fmaf(xn2, wr21.w, br1.w)));

        float mx = -1e30f, denom = 0.f;
        float a0 = 0.f, a1 = 0.f, a2 = 0.f, a3 = 0.f, a4 = 0.f, a5 = 0.f, a6 = 0.f, a7 = 0.f;

        float c0, c1, c2, n0, n1, n2;
        if (s < e) { int i0 = csr_src[s]; c0 = x[i0 * 3]; c1 = x[i0 * 3 + 1]; c2 = x[i0 * 3 + 2]; }
        if (s + 1 < e) { int i1 = csr_src[s + 1]; n0 = x[i1 * 3]; n1 = x[i1 * 3 + 1]; n2 = x[i1 * 3 + 2]; }
        for (int p = s; p < e; p++) {
            float t0, t1, t2;
            if (p + 2 < e) {
                int i2 = csr_src[p + 2];
                t0 = x[i2 * 3]; t1 = x[i2 * 3 + 1]; t2 = x[i2 * 3 + 2];
            }
            float4 v0, v1;
            v0.x = fmaf(c0, wl00.x, fmaf(c1, wl10.x, fmaf(c2, wl20.x, bl0.x)));
            v0.y = fmaf(c0, wl00.y, fmaf(c1, wl10.y, fmaf(c2, wl20.y, bl0.y)));
            v0.z = fmaf(c0, wl00.z, fmaf(c1, wl10.z, fmaf(c2, wl20.z, bl0.z)));
            v0.w = fmaf(c0, wl00.w, fmaf(c1, wl10.w, fmaf(c2, wl20.w, bl0.w)));
            v1.x = fmaf(c0, wl01.x, fmaf(c1, wl11.x, fmaf(c2, wl21.x, bl1.x)));
            v1.y = fmaf(c0, wl01.y, fmaf(c1, wl11.y, fmaf(c2, wl21.y, bl1.y)));
            v1.z = fmaf(c0, wl01.z, fmaf(c1, wl11.z, fmaf(c2, wl21.z, bl1.z)));
            v1.w = fmaf(c0, wl01.w, fmaf(c1, wl11.w, fmaf(c2, wl21.w, bl1.w)));
            float part;
            part = LK(v0.x + xr0.x) * at0.x;
            part = fmaf(LK(v0.y + xr0.y), at0.y, part);
            part = fmaf(LK(v0.z + xr0.z), at0.z, part);
            part = fmaf(LK(v0.w + xr0.w), at0.w, part);
            part = fmaf(LK(v1.x + xr1.x), at1.x, part);
            part = fmaf(LK(v1.y + xr1.y), at1.y, part);
            part = fmaf(LK(v1.z + xr1.z), at1.z, part);
            part = fmaf(LK(v1.w + xr1.w), at1.w, part);
            part += __shfl_xor(part, 1);
            part += __shfl_xor(part, 2);
            part += __shfl_xor(part, 4);
            part += __shfl_xor(part, 8);
            float mnew = fmaxf(mx, part);
            float scale = __expf(mx - mnew);
            float w = __expf(part - mnew);
            denom = fmaf(denom, scale, w);
            a0 = fmaf(a0, scale, w * v0.x);
            a1 = fmaf(a1, scale, w * v0.y);
            a2 = fmaf(a2, scale, w * v0.z);
            a3 = fmaf(a3, scale, w * v0.w);
            a4 = fmaf(a4, scale, w * v1.x);
            a5 = fmaf(a5, scale, w * v1.y);
            a6 = fmaf(a6, scale, w * v1.z);
            a7 = fmaf(a7, scale, w * v1.w);
            mx = mnew;
            c0 = n0; c1 = n1; c2 = n2;
            n0 = t0; n1 = t1; n2 = t2;
        }
        float inv = denom > 0.f ? 1.f / denom : 0.f;
        a0 *= inv; a1 *= inv; a2 *= inv; a3 *= inv;
        a4 *= inv; a5 *= inv; a6 *= inv; a7 *= inv;
        a0 += __shfl_xor(a0, 16); a0 += __shfl_xor(a0, 32);
        a1 += __shfl_xor(a1, 16); a1 += __shfl_xor(a1, 32);
        a2 += __shfl_xor(a2, 16); a2 += __shfl_xor(a2, 32);
        a3 += __shfl_xor(a3, 16); a3 += __shfl_xor(a3, 32);
        a4 += __shfl_xor(a4, 16); a4 += __shfl_xor(a4, 32);
        a5 += __shfl_xor(a5, 16); a5 += __shfl_xor(a5, 32);
        a6 += __shfl_xor(a6, 16); a6 += __shfl_xor(a6, 32);
        a7 += __shfl_xor(a7, 16); a7 += __shfl_xor(a7, 32);
        if (lane < 16) {
            float4 b0 = *(const float4*)(bias + lane * 8);
            float4 b1 = *(const float4*)(bias + lane * 8 + 4);
            float o[8];
            o[0] = fmaf(0.25f, a0, b0.x); o[1] = fmaf(0.25f, a1, b0.y);
            o[2] = fmaf(0.25f, a2, b0.z); o[3] = fmaf(0.25f, a3, b0.w);
            o[4] = fmaf(0.25f, a4, b1.x); o[5] = fmaf(0.25f, a5, b1.y);
            o[6] = fmaf(0.25f, a6, b1.z); o[7] = fmaf(0.25f, a7, b1.w);
#pragma unroll
            for (int j = 0; j < 8; j++) o[j] = o[j] > 0.f ? o[j] : (__expf(o[j]) - 1.f);
            *(float4*)(hout + (size_t)n * GAT_DIM + lane * 8) = make_float4(o[0], o[1], o[2], o[3]);
            *(float4*)(hout + (size_t)n * GAT_DIM + lane * 8 + 4) = make_float4(o[4], o[5], o[6], o[7]);
        }
    }
}

// ------- layers 1/2, R7: reverted to R5 non-persistent form ----------------
// (R5: dynamic block scheduling beats static striding; R6 batching regressed.)
__global__ __launch_bounds__(256) void fused_edge_kernel(const int* __restrict__ off,
                                                         const int* __restrict__ csr_src,
                                                         const __half* __restrict__ xl,
                                                         const __half* __restrict__ xr,
                                                         const float* __restrict__ att,
                                                         const float* __restrict__ bias,
                                                         float* __restrict__ hout) {
    int wid = threadIdx.x >> 6;
    int lane = threadIdx.x & 63;
    int n = blockIdx.x * 4 + wid;
    if (n >= N_NODES) return;
    int s = off[n], e = off[n + 1];
    const int loff = lane * 8;
    float4 xr0, xr1;
    {
        float4 rxr = *(const float4*)(xr + (size_t)n * FDIM + loff);
        const __half2* xp = (const __half2*)&rxr;
        float2 x01 = __half22float2(xp[0]);
        float2 x23 = __half22float2(xp[1]);
        float2 x45 = __half22float2(xp[2]);
        float2 x67 = __half22float2(xp[3]);
        xr0 = make_float4(x01.x, x01.y, x23.x, x23.y);
        xr1 = make_float4(x45.x, x45.y, x67.x, x67.y);
    }
    float4 at0 = *(const float4*)(att + loff);
    float4 at1 = *(const float4*)(att + loff + 4);

    float mx = -1e30f, denom = 0.f;
    float a0 = 0.f, a1 = 0.f, a2 = 0.f, a3 = 0.f, a4 = 0.f, a5 = 0.f, a6 = 0.f, a7 = 0.f;

    float4 rcur, rnext;
    if (s < e)     rcur  = *(const float4*)(xl + (size_t)csr_src[s] * FDIM + loff);
    if (s + 1 < e) rnext = *(const float4*)(xl + (size_t)csr_src[s + 1] * FDIM + loff);
    for (int p = s; p < e; p++) {
        float4 rt;
        if (p + 2 < e) rt = *(const float4*)(xl + (size_t)csr_src[p + 2] * FDIM + loff);
        float4 v0, v1;
        {
            const __half2* hp = (const __half2*)&rcur;
            float2 f01 = __half22float2(hp[0]);
            float2 f23 = __half22float2(hp[1]);
            float2 f45 = __half22float2(hp[2]);
            float2 f67 = __half22float2(hp[3]);
            v0 = make_float4(f01.x, f01.y, f23.x, f23.y);
            v1 = make_float4(f45.x, f45.y, f67.x, f67.y);
        }
        float part;
        part = LK(v0.x + xr0.x) * at0.x;
        part = fmaf(LK(v0.y + xr0.y), at0.y, part);
        part = fmaf(LK(v0.z + xr0.z), at0.z, part);
        part = fmaf(LK(v0.w + xr0.w), at0.w, part);
        part = fmaf(LK(v1.x + xr1.x), at1.x, part);
        part = fmaf(LK(v1.y + xr1.y), at1.y, part);
        part = fmaf(LK(v1.z + xr1.z), at1.z, part);
        part = fmaf(LK(v1.w + xr1.w), at1.w, part);
        part += __shfl_xor(part, 1);
        part += __shfl_xor(part, 2);
        part += __shfl_xor(part, 4);
        part += __shfl_xor(part, 8);
        float mnew = fmaxf(mx, part);
        float scale = __expf(mx - mnew);
        float w = __expf(part - mnew);
        denom = fmaf(denom, scale, w);
        a0 = fmaf(a0, scale, w * v0.x);
        a1 = fmaf(a1, scale, w * v0.y);
        a2 = fmaf(a2, scale, w * v0.z);
        a3 = fmaf(a3, scale, w * v0.w);
        a4 = fmaf(a4, scale, w * v1.x);
        a5 = fmaf(a5, scale, w * v1.y);
        a6 = fmaf(a6, scale, w * v1.z);
        a7 = fmaf(a7, scale, w * v1.w);
        mx = mnew;
        rcur = rnext;
        rnext = rt;
    }
    float inv = denom > 0.f ? 1.f / denom : 0.f;
    a0 *= inv; a1 *= inv; a2 *= inv; a3 *= inv;
    a4 *= inv; a5 *= inv; a6 *= inv; a7 *= inv;
    a0 += __shfl_xor(a0, 16); a0 += __shfl_xor(a0, 32);
    a1 += __shfl_xor(a1, 16); a1 += __shfl_xor(a1, 32);
    a2 += __shfl_xor(a2, 16); a2 += __shfl_xor(a2, 32);
    a3 += __shfl_xor(a3, 16); a3 += __shfl_xor(a3, 32);
    a4 += __shfl_xor(a4, 16); a4 += __shfl_xor(a4, 32);
    a5 += __shfl_xor(a5, 16); a5 += __shfl_xor(a5, 32);
    a6 += __shfl_xor(a6, 16); a6 += __shfl_xor(a6, 32);
    a7 += __shfl_xor(a7, 16); a7 += __shfl_xor(a7, 32);
    if (lane < 16) {
        float4 b0 = *(const float4*)(bias + lane * 8);
        float4 b1 = *(const float4*)(bias + lane * 8 + 4);
        float o[8];
        o[0] = fmaf(0.25f, a0, b0.x); o[1] = fmaf(0.25f, a1, b0.y);
        o[2] = fmaf(0.25f, a2, b0.z); o[3] = fmaf(0.25f, a3, b0.w);
        o[4] = fmaf(0.25f, a4, b1.x); o[5] = fmaf(0.25f, a5, b1.y);
        o[6] = fmaf(0.25f, a6, b1.z); o[7] = fmaf(0.25f, a7, b1.w);
#pragma unroll
        for (int j = 0; j < 8; j++) o[j] = o[j] > 0.f ? o[j] : (__expf(o[j]) - 1.f);
        *(float4*)(hout + (size_t)n * GAT_DIM + lane * 8) = make_float4(o[0], o[1], o[2], o[3]);
        *(float4*)(hout + (size_t)n * GAT_DIM + lane * 8 + 4) = make_float4(o[4], o[5], o[6], o[7]);
    }
}

// ---------------- mean pool over sorted batch (double accumulation) ----------------
#define POOL_CHUNK 64
__global__ __launch_bounds__(128) void pool_kernel(const float* __restrict__ h,
                                                   const int* __restrict__ batch,
                                                   double* __restrict__ psum,
                                                   int* __restrict__ pcnt) {
    int c = threadIdx.x;  // 0..127
    int n0 = blockIdx.x * POOL_CHUNK;
    int n1 = min(n0 + POOL_CHUNK, N_NODES);
    if (n0 >= N_NODES) return;
    double acc = 0.0;
    int cur = batch[n0];
    int cnt = 0;
    for (int n = n0; n < n1; n++) {
        int g = batch[n];
        if (g != cur) {
            atomicAdd(&psum[(size_t)cur * GAT_DIM + c], acc);
            if (c == 0) atomicAdd(&pcnt[cur], cnt);
            acc = 0.0; cnt = 0; cur = g;
        }
        acc += (double)h[(size_t)n * GAT_DIM + c];
        cnt++;
    }
    atomicAdd(&psum[(size_t)cur * GAT_DIM + c], acc);
    if (c == 0) atomicAdd(&pcnt[cur], cnt);
}

// ---------------- final linear: out[64,128] = g @ linW + linb ----------------
__global__ __launch_bounds__(128) void final_kernel(const double* __restrict__ psum,
                                                    const int* __restrict__ pcnt,
                                                    const float* __restrict__ linW,
                                                    const float* __restrict__ linb,
                                                    float* __restrict__ out) {
    int g = blockIdx.x;       // 0..63
    int j = threadIdx.x;      // 0..127
    __shared__ float gv[128];
    float cnt = (float)max(pcnt[g], 1);
    gv[j] = (float)(psum[(size_t)g * 128 + j] / (double)cnt);
    __syncthreads();
    float acc = 0.f;
    for (int c = 0; c < 128; c++) acc = fmaf(gv[c], linW[c * 128 + j], acc);
    out[(size_t)g * 128 + j] = acc + linb[j];
}

extern "C" void kernel_launch(void* const* d_in, const int* in_sizes, int n_in,
                              void* d_out, int out_size, void* d_ws, size_t ws_size,
                              hipStream_t stream) {
    const float* x    = (const float*)d_in[0];
    const int* eidx   = (const int*)d_in[1];
    const int* batch  = (const int*)d_in[2];
    const float* Wl[3] = {(const float*)d_in[3],  (const float*)d_in[9],  (const float*)d_in[15]};
    const float* bl[3] = {(const float*)d_in[4],  (const float*)d_in[10], (const float*)d_in[16]};
    const float* Wr[3] = {(const float*)d_in[5],  (const float*)d_in[11], (const float*)d_in[17]};
    const float* br[3] = {(const float*)d_in[6],  (const float*)d_in[12], (const float*)d_in[18]};
    const float* att[3] = {(const float*)d_in[7], (const float*)d_in[13], (const float*)d_in[19]};
    const float* bb[3] = {(const float*)d_in[8],  (const float*)d_in[14], (const float*)d_in[20]};
    const float* linW = (const float*)d_in[21];
    const float* linb = (const float*)d_in[22];
    float* out = (float*)d_out;

    const int* esrc = eidx;
    const int* edst = eidx + N_EDGES;

    // workspace carve-up (256B aligned)
    char* p = (char*)d_ws;
    auto alloc = [&](size_t bytes) { void* r = (void*)p; p += (bytes + 255) & ~(size_t)255; return r; };
    __half* xl     = (__half*)alloc((size_t)N_NODES * FDIM * 2);  // 51.2 MB (fp16)
    __half* xr     = (__half*)alloc((size_t)N_NODES * FDIM * 2);  // 51.2 MB (fp16)
    float* hbuf    = (float*)alloc((size_t)N_NODES * GAT_DIM * 4);// 25.6 MB
    int*   off     = (int*)alloc((size_t)(N_NODES + 1) * 4);
    int*   csr_src = (int*)alloc((size_t)N_EDGES * 4);
    __half* Wt1    = (__half*)alloc((size_t)1024 * 128 * 2);
    __half* Wt2    = (__half*)alloc((size_t)1024 * 128 * 2);
    float* bc1     = (float*)alloc((size_t)1024 * 4);
    float* bc2     = (float*)alloc((size_t)1024 * 4);
    // --- contiguous zero region: deg, cursor, psum, pcnt ---
    char* zbase = p;
    int*   deg     = (int*)alloc((size_t)N_NODES * 4);
    int*   cursor  = (int*)alloc((size_t)N_NODES * 4);
    double* psum   = (double*)alloc((size_t)N_GRAPHS * GAT_DIM * 8);
    int*   pcnt    = (int*)alloc((size_t)N_GRAPHS * 4);
    size_t zbytes = (size_t)(p - zbase);

    hipMemsetAsync(zbase, 0, zbytes, stream);

    // CSR build + weight prep
    deg_kernel<<<(N_EDGES + 255) / 256, 256, 0, stream>>>(edst, deg);
    scan_kernel<<<1, 1024, 0, stream>>>(deg, off);
    fill_kernel<<<(N_EDGES + 255) / 256, 256, 0, stream>>>(esrc, edst, off, cursor, csr_src);
    wprep_kernel<<<1024, 128, 0, stream>>>(Wl[1], Wr[1], bl[1], br[1], Wt1, bc1);
    wprep_kernel<<<1024, 128, 0, stream>>>(Wl[2], Wr[2], bl[2], br[2], Wt2, bc2);

    const int ggrid = (N_NODES + GM - 1) / GM;   // 782 blocks, each loops 8 col tiles
    const int egrid = (N_NODES + 3) / 4;         // 4 nodes (waves) per 256-thr block

    // layer 0: fully fused (K=3 transform recomputed per edge), persistent waves
    fused_edge0_kernel<<<EW0_BLOCKS, 256, 0, stream>>>(off, csr_src, x, Wl[0], bl[0],
                                                       Wr[0], br[0], att[0], bb[0], hbuf);
    // layers 1,2
    __half* Wt[3] = {nullptr, Wt1, Wt2};
    float*  bc[3] = {nullptr, bc1, bc2};
    for (int l = 1; l < 3; l++) {
        gemm_mfma_kernel<<<ggrid, 256, 0, stream>>>(hbuf, Wt[l], bc[l], xl, xr, N_NODES);
        fused_edge_kernel<<<egrid, 256, 0, stream>>>(off, csr_src, xl, xr,
                                                     att[l], bb[l], hbuf);
    }

    pool_kernel<<<(N_NODES + POOL_CHUNK - 1) / POOL_CHUNK, 128, 0, stream>>>(hbuf, batch, psum, pcnt);
    final_kernel<<<N_GRAPHS, 128, 0, stream>>>(psum, pcnt, linW, linb, out);
}